// Round 1
// baseline (647.881 us; speedup 1.0000x reference)
//
#include <hip/hip_runtime.h>
#include <math.h>

// Problem constants (from reference): D=128 (=H*DK), HH=256 hyper hidden.
#define DD 128
#define HHID 256

// ---------- tiny hypernetwork: pref -> mid[4] ----------
__global__ void k_hyper(const float* __restrict__ pref,
                        const float* __restrict__ fc1_w, const float* __restrict__ fc1_b,
                        const float* __restrict__ fc2_w, const float* __restrict__ fc2_b,
                        const float* __restrict__ fc3_w, const float* __restrict__ fc3_b,
                        float* __restrict__ mid_out) {
    __shared__ float h1[HHID];
    __shared__ float h2[HHID];
    int t = threadIdx.x;
    float p0 = pref[0], p1 = pref[1];
    h1[t] = fc1_w[t * 2 + 0] * p0 + fc1_w[t * 2 + 1] * p1 + fc1_b[t];
    __syncthreads();
    float acc = fc2_b[t];
    for (int i = 0; i < HHID; ++i) acc += fc2_w[t * HHID + i] * h1[i];
    h2[t] = acc;
    __syncthreads();
    if (t < 4) {
        float m = fc3_b[t];
        for (int i = 0; i < HHID; ++i) m += fc3_w[t * HHID + i] * h2[i];
        mid_out[t] = m;
    }
}

// ---------- M[b,b'] = sum_a Wq[a,b] * Wk[a,b'] / (H*sqrt(D)) ----------
// Wq_flat[i] = wq_w[i,0]*mid0 + wq_w[i,1]*mid1 ; Wk uses mid2, mid3.
__global__ void k_build_M(const float* __restrict__ wq_w, const float* __restrict__ wk_w,
                          const float* __restrict__ mid, float* __restrict__ M_) {
    int b = blockIdx.x;    // first index of M
    int t = threadIdx.x;   // second index of M
    float m0 = mid[0], m1 = mid[1], m2 = mid[2], m3 = mid[3];
    const float scale = 0.011048543456f;  // 1/(8*sqrt(128))
    float acc = 0.f;
    for (int a = 0; a < DD; ++a) {
        int iq = a * DD + b;
        float wq = wq_w[iq * 2 + 0] * m0 + wq_w[iq * 2 + 1] * m1;
        int ik = a * DD + t;
        float wk = wk_w[ik * 2 + 0] * m2 + wk_w[ik * 2 + 1] * m3;
        acc += wq * wk;
    }
    M_[b * DD + t] = acc * scale;
}

// ---------- group counts ----------
__global__ void k_count(const int* __restrict__ seg, unsigned* __restrict__ counts, int E_) {
    int e = blockIdx.x * blockDim.x + threadIdx.x;
    if (e < E_) atomicAdd(&counts[seg[e]], 1u);
}

// ---------- zero only multi-group rows (avoids 256MB memset) ----------
__global__ void k_zero_rows(const int* __restrict__ seg, const unsigned* __restrict__ counts,
                            float* __restrict__ gs, int E_) {
    int wave = (int)((blockIdx.x * blockDim.x + threadIdx.x) >> 6);
    int lane = threadIdx.x & 63;
    if (wave >= E_) return;
    int g = seg[wave];
    if (counts[g] < 2) return;
    gs[g * DD + lane] = 0.f;        // redundant writes of 0 across group members are benign
    gs[g * DD + lane + 64] = 0.f;
}

// ---------- scatter emb into group sums (multi groups only) ----------
__global__ void k_scatter(const int* __restrict__ seg, const unsigned* __restrict__ counts,
                          const float* __restrict__ emb, float* __restrict__ gs, int E_) {
    int wave = (int)((blockIdx.x * blockDim.x + threadIdx.x) >> 6);
    int lane = threadIdx.x & 63;
    if (wave >= E_) return;
    int g = seg[wave];
    if (counts[g] < 2) return;
    atomicAdd(&gs[g * DD + lane],      emb[wave * DD + lane]);
    atomicAdd(&gs[g * DD + lane + 64], emb[wave * DD + lane + 64]);
}

// ---------- per-group t_g = M^T * (sum_g / c), overwrite gs row ----------
__global__ void k_group_t(const unsigned* __restrict__ counts, const float* __restrict__ M_,
                          float* __restrict__ gs, int E_) {
    int g = (int)((blockIdx.x * blockDim.x + threadIdx.x) >> 6);
    int lane = threadIdx.x & 63;
    if (g >= E_) return;
    unsigned c = counts[g];
    if (c < 2) return;
    float acc0 = 0.f, acc1 = 0.f;
    for (int d = 0; d < DD; ++d) {
        float m = gs[g * DD + d];                  // broadcast read of the sum row
        acc0 += m * M_[d * DD + lane];             // coalesced M row read
        acc1 += m * M_[d * DD + lane + 64];
    }
    float inv = 1.0f / (float)c;
    // acc depends on ALL loads above -> compiler waits them out before the stores;
    // only this wave touches row g, so read-then-overwrite is safe.
    gs[g * DD + lane] = acc0 * inv;
    gs[g * DD + lane + 64] = acc1 * inv;
}

// ---------- order-preserving float<->uint for atomicMax ----------
__device__ inline unsigned enc_f(float f) {
    unsigned u = __float_as_uint(f);
    return (u & 0x80000000u) ? ~u : (u | 0x80000000u);
}
__device__ inline float dec_f(unsigned k) {
    return (k & 0x80000000u) ? __uint_as_float(k ^ 0x80000000u) : __uint_as_float(~k);
}

// ---------- per-edge score (multi only): s = 10*tanh(t_g . k_e - d_e/sqrt(2)) ----------
__global__ void k_score(const int* __restrict__ seg, const unsigned* __restrict__ counts,
                        const float* __restrict__ emb, const float* __restrict__ gs,
                        const float* __restrict__ dists, const float* __restrict__ pref,
                        float* __restrict__ scores, unsigned* __restrict__ smax, int E_) {
    int e = (int)((blockIdx.x * blockDim.x + threadIdx.x) >> 6);
    int lane = threadIdx.x & 63;
    if (e >= E_) return;
    int g = seg[e];
    if (counts[g] < 2) return;
    float acc = gs[g * DD + lane] * emb[e * DD + lane]
              + gs[g * DD + lane + 64] * emb[e * DD + lane + 64];
    for (int off = 32; off; off >>= 1) acc += __shfl_down(acc, off, 64);
    if (lane == 0) {
        float de = pref[0] * dists[e * 2 + 0] + pref[1] * dists[e * 2 + 1];
        float s = acc - de * 0.7071067811865475f;
        s = 10.0f * tanhf(s);
        scores[e] = s;
        atomicMax(&smax[g], enc_f(s));
    }
}

// ---------- exp + group denominator ----------
__global__ void k_expsum(const int* __restrict__ seg, const unsigned* __restrict__ counts,
                         const unsigned* __restrict__ smax, float* __restrict__ scores,
                         float* __restrict__ denom, int E_) {
    int e = blockIdx.x * blockDim.x + threadIdx.x;
    if (e >= E_) return;
    int g = seg[e];
    if (counts[g] < 2) return;
    float ex = expf(scores[e] - dec_f(smax[g]));
    scores[e] = ex;
    atomicAdd(&denom[g], ex);
}

// ---------- final probs (singletons are exactly 1.0) ----------
__global__ void k_final(const int* __restrict__ seg, const unsigned* __restrict__ counts,
                        const float* __restrict__ scores, const float* __restrict__ denom,
                        float* __restrict__ out, int E_) {
    int e = blockIdx.x * blockDim.x + threadIdx.x;
    if (e >= E_) return;
    int g = seg[e];
    out[e] = (counts[g] < 2) ? 1.0f : scores[e] / denom[g];
}

extern "C" void kernel_launch(void* const* d_in, const int* in_sizes, int n_in,
                              void* d_out, int out_size, void* d_ws, size_t ws_size,
                              hipStream_t stream) {
    const float* pref  = (const float*)d_in[0];
    const float* dists = (const float*)d_in[1];
    const float* emb   = (const float*)d_in[2];
    const int*   seg   = (const int*)d_in[3];
    const float* fc1_w = (const float*)d_in[4];
    const float* fc1_b = (const float*)d_in[5];
    const float* fc2_w = (const float*)d_in[6];
    const float* fc2_b = (const float*)d_in[7];
    const float* fc3_w = (const float*)d_in[8];
    const float* fc3_b = (const float*)d_in[9];
    const float* wq_w  = (const float*)d_in[10];
    const float* wk_w  = (const float*)d_in[11];
    int E_ = in_sizes[3];
    float* out = (float*)d_out;

    // workspace layout: mid(256B) | M(64KB) | counts(E) | smax(E) | denom(E) | scores(E) | gs(E*128)
    char* ws = (char*)d_ws;
    float*    mid    = (float*)ws;
    float*    M_     = (float*)(ws + 256);
    char* p = ws + 256 + DD * DD * 4;
    unsigned* counts = (unsigned*)p;  p += (size_t)E_ * 4;
    unsigned* smax   = (unsigned*)p;  p += (size_t)E_ * 4;
    float*    denom  = (float*)p;     p += (size_t)E_ * 4;
    float*    scores = (float*)p;     p += (size_t)E_ * 4;
    float*    gs     = (float*)p;     p += (size_t)E_ * (size_t)DD * 4;
    if ((size_t)(p - ws) > ws_size) return;  // graceful (wrong) failure instead of OOB crash

    // counts, smax, denom are contiguous -> one async memset (capture-safe)
    hipMemsetAsync(counts, 0, (size_t)E_ * 12, stream);

    k_hyper<<<1, HHID, 0, stream>>>(pref, fc1_w, fc1_b, fc2_w, fc2_b, fc3_w, fc3_b, mid);
    k_build_M<<<DD, DD, 0, stream>>>(wq_w, wk_w, mid, M_);

    int tb = 256;
    int eb = (E_ + tb - 1) / tb;
    int wb = (E_ + 3) / 4;  // one 64-lane wave per edge/group, 4 waves per block
    k_count<<<eb, tb, 0, stream>>>(seg, counts, E_);
    k_zero_rows<<<wb, 256, 0, stream>>>(seg, counts, gs, E_);
    k_scatter<<<wb, 256, 0, stream>>>(seg, counts, emb, gs, E_);
    k_group_t<<<wb, 256, 0, stream>>>(counts, M_, gs, E_);
    k_score<<<wb, 256, 0, stream>>>(seg, counts, emb, gs, dists, pref, scores, smax, E_);
    k_expsum<<<eb, tb, 0, stream>>>(seg, counts, smax, scores, denom, E_);
    k_final<<<eb, tb, 0, stream>>>(seg, counts, scores, denom, out, E_);
}